// Round 9
// baseline (205.319 us; speedup 1.0000x reference)
//
#include <hip/hip_runtime.h>
#include <math.h>

// Problem constants (match reference)
#define B_    4
#define T_    2048
#define D_    1024
#define F_    4096
#define R_    (B_*T_)      // 8192 rows (b,t)
#define SEG_  64           // segments per time-chain
#define L_    (T_/SEG_)    // 32 steps per segment
#define DECAYF 0.9f
#define OMDF   0.1f        // 1 - decay
// Flag threshold below 0.5: the k4 fallback re-tests at exactly 0.5 in fp32,
// so flags only need NO FALSE NEGATIVES. fp8(x8-scaled) GEMM error is
// ~1e-3 RMS (6-sigma ~7e-3); margin 0.05 is ~7x worst plausible error.
#define FLAG_THRESH 0.45f

// ---------------------------------------------------------------------------
// K2 HISTORY (do not re-litigate):
//  R1/R8 depth-4 source (compiler-collapsed to VGPR=104, 4 waves/SIMD):
//      44.2 us, FETCH 53 MB. L2-BW-bound: each tile read by 2 waves ->
//      1 GB L2 traffic / ~23 TB/s == 44 us.
//  R0  2-stage unrolled-x2 source: VGPR=224, 2 waves/SIMD, 55.7 us.
//  R2  asm-opaque depth-4: CRASHED. R3 acc[2][4]: SPILLED (VGPR 256).
//  R4  __syncthreads lockstep (register streams): dedupe PROVEN (FETCH
//      16 MB) but drain of just-issued loads serialized: 69.6 us.
//  R5  raw s_barrier lockstep: dedupe held, 51.6 us. Lockstep-on-registers
//      ABANDONED.
//  R9  (this) catalog 2-phase LDS template: global_load_lds stages each
//      tile ONCE per block (structural dedupe, 512 MB L2 traffic) and the
//      barrier drain hits only old stage-loads. Falls back to R8 if >= 44.
// ---------------------------------------------------------------------------

typedef __attribute__((ext_vector_type(4)))  int   i32x4;
typedef __attribute__((ext_vector_type(8)))  int   i32x8;
typedef __attribute__((ext_vector_type(16))) float f32x16;

// pack 4 floats into 4 fp8 e4m3 bytes (byte0 = first arg)
__device__ __forceinline__ int pk_fp8x4(float x, float y, float z, float w) {
    int p = 0;
    p = __builtin_amdgcn_cvt_pk_fp8_f32(x, y, p, false);  // bytes 0,1
    p = __builtin_amdgcn_cvt_pk_fp8_f32(z, w, p, true);   // bytes 2,3
    return p;
}

// ---------------------------------------------------------------------------
// PACKED OPERAND LAYOUT (R9): emit fp8 arrays in MFMA-operand tile order:
//   panel P = row>>5 (32 rows), k-chunk C = kbyte>>6 (64 B) -> 2 KB tile at
//   byte ((P*16 + C) * 2048). Within a tile, byte  h*1024 + l*16 + t  holds
//   element [row = P*32 + (l&31)][k = C*64 + (l>>5)*32 + h*16 + t].
// A wave's 32x32x64 fragment = two contiguous 1 KB spans (lane l at l*16,
// halves at +0/+1024) — coalesced 16B/lane, and exactly the layout
// global_load_lds writes (uniform base + lane*16).
__device__ __forceinline__ size_t pk_off(int row, int d) {
    // byte offset of element [row][d] in the packed layout
    return ((size_t)((row >> 5) * 16 + (d >> 6)) * 2048)
         + ((d >> 4) & 1) * 1024
         + ((row & 31) + ((d >> 5) & 1) * 32) * 16
         + (d & 15);
}

// ---------------------------------------------------------------------------
// KA: fused prologue. Grid-partitioned roles:
//   blocks [0, 4096):       W1 fp32 -> fp8 e4m3 x8, packed operand layout
//   blocks [4096, 4352):    per-segment EMA end-state (seg_sum)
//   blocks [4352, 4384):    zero the 8192 per-row spike flags
#define KA_W1_BLOCKS  4096
#define KA_SEG_BLOCKS 256
#define KA_FLAG_BLOCKS 32

__global__ __launch_bounds__(256)
void kA_prologue(const float* __restrict__ spikes,
                 const float* __restrict__ W1,
                 unsigned char* __restrict__ w_f8,
                 float* __restrict__ seg_sum,
                 unsigned int* __restrict__ flags) {
    const int bid = blockIdx.x;
    const int tid = threadIdx.x;
    if (bid < KA_W1_BLOCKS) {
        int i = bid * 256 + tid;                  // float4 index over W1 [F x D]
        float4 v = ((const float4*)W1)[i];
        int f  = i >> 8;                          // D/4 = 256 groups per row
        int d0 = (i & 255) * 4;
        *(int*)(w_f8 + pk_off(f, d0)) = pk_fp8x4(8.f*v.x, 8.f*v.y, 8.f*v.z, 8.f*v.w);
    } else if (bid < KA_W1_BLOCKS + KA_SEG_BLOCKS) {
        int t = (bid - KA_W1_BLOCKS) * 256 + tid; // B_*SEG_*D_/4 threads
        int dg = t & (D_ / 4 - 1);
        int s = (t >> 8) & (SEG_ - 1);
        int b = t >> 14;
        const float4* sp4 = (const float4*)spikes;
        const int base = (b * T_ + s * L_) * (D_ / 4) + dg;
        float4 e = {0.f, 0.f, 0.f, 0.f};
#pragma unroll 8
        for (int k = 0; k < L_; ++k) {
            float4 x = sp4[base + k * (D_ / 4)];
            e.x = DECAYF * e.x + OMDF * x.x;
            e.y = DECAYF * e.y + OMDF * x.y;
            e.z = DECAYF * e.z + OMDF * x.z;
            e.w = DECAYF * e.w + OMDF * x.w;
        }
        ((float4*)seg_sum)[(b * SEG_ + s) * (D_ / 4) + dg] = e;
    } else {
        int i = (bid - KA_W1_BLOCKS - KA_SEG_BLOCKS) * 256 + tid;
        if (i < R_) flags[i] = 0u;
    }
}

// ---------------------------------------------------------------------------
// KB: weighted Kogge-Stone scan over the 64 segments of each (b,d) chain,
// one chain per 64-lane wave (lane = segment). start_state[s] = scan[s-1].
__global__ __launch_bounds__(256)
void kB_seg_scan(const float* __restrict__ seg_sum,
                 float* __restrict__ start_state) {
    int g = blockIdx.x * 256 + threadIdx.x;   // B_*D_*64 threads
    int s = g & 63;                           // segment = lane
    int c = g >> 6;                           // chain id: 0..B_*D_-1
    int d = c & (D_ - 1);
    int b = c >> 10;
    int idx = (b * SEG_ + s) * D_ + d;
    float v = seg_sum[idx];
    float wp = 0.0343368382f;                 // 0.9^32 (per-segment decay)
#pragma unroll
    for (int off = 1; off < SEG_; off <<= 1) {
        float u = __shfl_up(v, off, 64);
        if (s >= off) v += wp * u;
        wp *= wp;                             // w^1, w^2, w^4, ...
    }
    float pv = __shfl_up(v, 1, 64);
    start_state[idx] = (s == 0) ? 0.f : pv;
}

// ---------------------------------------------------------------------------
// KC: recompute segment-local EMA seeded with start_state; emit fp8 (x8)
// into the packed operand layout.
__global__ __launch_bounds__(256)
void kC_ema_fp8(const float* __restrict__ spikes,
                const float* __restrict__ start_state,
                unsigned char* __restrict__ a_f8) {
    int t = blockIdx.x * 256 + threadIdx.x;            // B_*SEG_*D_/4 threads
    int dg = t & (D_ / 4 - 1);
    int s = (t >> 8) & (SEG_ - 1);
    int b = t >> 14;
    const float4* sp4 = (const float4*)spikes;
    const int base = (b * T_ + s * L_) * (D_ / 4) + dg;
    const int d0 = dg * 4;
    unsigned char* dst = a_f8 + pk_off(b * T_ + s * L_, d0);   // k=0 element
    float4 e = ((const float4*)start_state)[(b * SEG_ + s) * (D_ / 4) + dg];
#pragma unroll 8
    for (int k = 0; k < L_; ++k) {
        float4 x = sp4[base + k * (D_ / 4)];
        e.x = DECAYF * e.x + OMDF * x.x;
        e.y = DECAYF * e.y + OMDF * x.y;
        e.z = DECAYF * e.z + OMDF * x.z;
        e.w = DECAYF * e.w + OMDF * x.w;
        *(int*)(dst + k * 16) = pk_fp8x4(8.f*e.x, 8.f*e.y, 8.f*e.z, 8.f*e.w);
    }
}

// ---------------------------------------------------------------------------
// K2 (R9): catalog 2-phase LDS template (T3 minimum form, verified in
// learn_hip m230/m248). Per 128x128 block, each K-chunk's 16 KB working set
// (4 A-tiles + 4 B-tiles x 2 KB) is staged into LDS ONCE via
// global_load_lds (wave w stages tiles 2w,2w+1 = 4 x 16B-wide loads), then
// both reader waves ds_read_b128 their fragments from LDS.
//   - L2 traffic: 16 KB x 16 chunks x 2048 blocks = 512 MB (half of R8's
//     1 GB register-streaming redundancy) -> ~22 us BW floor.
//   - Double buffer (2 x 16 KB): STAGE(C+1, buf^1) issues at chunk top;
//     __syncthreads() at chunk end provides the counted guarantee: its
//     vmcnt(0) drains only THIS wave's 4 stage-loads issued one full
//     compute phase earlier (mostly landed), then the barrier joins all
//     waves -> next chunk's reads are safe. Buffer overwrite is protected
//     by the previous chunk's barrier (lgkmcnt(0) drained the reads).
//   - Unlike R4: no just-issued register loads are drained, and the
//     dedupe is structural (not timing-dependent).
// NOTE: plain __launch_bounds__(256); acc[2][2] only. Target VGPR <= 128
// (4 waves/SIMD): 64 acc + 32 frag + addressing.
__global__ __launch_bounds__(256)
void k2_mfma_flags(const unsigned char* __restrict__ Ap,  // packed a_f8
                   const unsigned char* __restrict__ Bp,  // packed w_f8
                   unsigned int* __restrict__ flags) {
    const int tid = threadIdx.x;
    const int w = tid >> 6;
    const int lane = tid & 63;
    // XCD-chunked swizzle (T1): 2048 blocks, 8 XCDs, 256 blocks/XCD.
    // Bijective since 2048 % 8 == 0. n-fast: A-panel stays L2-hot.
    const int orig = blockIdx.x;
    const int swz  = (orig & 7) * 256 + (orig >> 3);
    const int m0 = (swz >> 5) * 128;     // 64 m-tiles, slow
    const int n0 = (swz & 31) * 128;     // 32 n-tiles, fast
    const int wm = w >> 1, wn = w & 1;
    const int kg = lane >> 5;

    __shared__ unsigned char lbuf[2][16384];   // 2 x (8 tiles x 2 KB)

    // Staging sources: wave w owns tiles 2w, 2w+1 (tiles 0-3 = A panels,
    // 4-7 = B panels). Per-lane global address = tile base + lane*16;
    // global_load_lds writes LDS at uniform base + lane*16 (m104) — which
    // is exactly the packed-tile layout, so LDS mirrors global bytes.
    const unsigned char* g0;
    const unsigned char* g1;
    if (w < 2) {
        g0 = Ap + ((size_t)((m0 >> 5) + 2 * w    ) * 16) * 2048 + lane * 16;
        g1 = Ap + ((size_t)((m0 >> 5) + 2 * w + 1) * 16) * 2048 + lane * 16;
    } else {
        g0 = Bp + ((size_t)((n0 >> 5) + 2 * (w - 2)    ) * 16) * 2048 + lane * 16;
        g1 = Bp + ((size_t)((n0 >> 5) + 2 * (w - 2) + 1) * 16) * 2048 + lane * 16;
    }
    const int lt0 = (2 * w) * 2048;            // this wave's LDS dst tiles
    const int lt1 = (2 * w + 1) * 2048;

#define GLDS(gp, loff)                                                      \
    __builtin_amdgcn_global_load_lds(                                       \
        (const __attribute__((address_space(1))) void*)(gp),                \
        (__attribute__((address_space(3))) void*)(&lbuf[0][0] + (loff)),    \
        16, 0, 0)

    // Issue one chunk's staging (4 x global_load_lds_dwordx4 per wave).
#define STAGE(C, buf)                                                       \
    GLDS(g0 + (size_t)(C) * 2048,        (buf) * 16384 + lt0);              \
    GLDS(g0 + (size_t)(C) * 2048 + 1024, (buf) * 16384 + lt0 + 1024);       \
    GLDS(g1 + (size_t)(C) * 2048,        (buf) * 16384 + lt1);              \
    GLDS(g1 + (size_t)(C) * 2048 + 1024, (buf) * 16384 + lt1 + 1024);

    f32x16 acc[2][2] = {};

    // Fragment read offsets within a buffer (contiguous b128 per lane —
    // conflict-free): A tiles wm*2(+1), B tiles 4+wn*2(+1).
    const int aoff0 = (wm * 2    ) * 2048 + lane * 16;
    const int aoff1 = (wm * 2 + 1) * 2048 + lane * 16;
    const int boff0 = (4 + wn * 2    ) * 2048 + lane * 16;
    const int boff1 = (4 + wn * 2 + 1) * 2048 + lane * 16;

#define LDSF(off, buf)                                                      \
    ({ i32x4 lo_ = *(const i32x4*)(&lbuf[0][0] + (buf) * 16384 + (off));    \
       i32x4 hi_ = *(const i32x4*)(&lbuf[0][0] + (buf) * 16384 + (off) + 1024); \
       (i32x8){lo_.x, lo_.y, lo_.z, lo_.w, hi_.x, hi_.y, hi_.z, hi_.w}; })

#define MFMA4(AF0, AF1, BF0, BF1)                                           \
    {                                                                       \
        acc[0][0] = __builtin_amdgcn_mfma_scale_f32_32x32x64_f8f6f4(        \
            AF0, BF0, acc[0][0], 0, 0, 0, 124, 0, 124);                     \
        acc[0][1] = __builtin_amdgcn_mfma_scale_f32_32x32x64_f8f6f4(        \
            AF0, BF1, acc[0][1], 0, 0, 0, 124, 0, 124);                     \
        acc[1][0] = __builtin_amdgcn_mfma_scale_f32_32x32x64_f8f6f4(        \
            AF1, BF0, acc[1][0], 0, 0, 0, 124, 0, 124);                     \
        acc[1][1] = __builtin_amdgcn_mfma_scale_f32_32x32x64_f8f6f4(        \
            AF1, BF1, acc[1][1], 0, 0, 0, 124, 0, 124);                     \
    }

    // Prologue: stage chunk 0; the syncthreads' vmcnt(0)+barrier makes
    // buf0 visible to all waves.
    STAGE(0, 0)
    __syncthreads();

#pragma unroll
    for (int C = 0; C < 16; ++C) {
        const int buf = C & 1;
        if (C < 15) { STAGE(C + 1, buf ^ 1) }
        i32x8 A0 = LDSF(aoff0, buf), A1 = LDSF(aoff1, buf);
        i32x8 B0 = LDSF(boff0, buf), B1 = LDSF(boff1, buf);
        MFMA4(A0, A1, B0, B1);
        if (C < 15) __syncthreads();
    }
#undef GLDS
#undef STAGE
#undef LDSF
#undef MFMA4

    // Epilogue: per-row spike flags. 32x32 C/D layout (m74/m101-verified):
    // col = lane&31, row = (reg&3) + 8*(reg>>2) + 4*(lane>>5).
#pragma unroll
    for (int i = 0; i < 2; ++i) {
#pragma unroll
        for (int reg = 0; reg < 16; ++reg) {
            float mx = fmaxf(acc[i][0][reg], acc[i][1][reg]);
            if (mx > FLAG_THRESH) {
                const int rr = (reg & 3) + 8 * (reg >> 2) + 4 * kg;
                atomicOr(&flags[m0 + wm * 64 + i * 32 + rr], 1u);
            }
        }
    }
}

// ---------------------------------------------------------------------------
// K4: one block per (b,t) row. Unflagged rows (the overwhelmingly common
// case) write zeros. Flagged rows take the exact fp32 slow path, rebuilding
// the EMA row from start_state + <=32 spike rows.
__global__ __launch_bounds__(256)
void k4_output(const float* __restrict__ spikes,
               const float* __restrict__ start_state,
               const float* __restrict__ W1,
               const float* __restrict__ Wr,
               const float* __restrict__ W2,
               const unsigned int* __restrict__ flags,
               float* __restrict__ out) {
    const int row = blockIdx.x;          // 0..R_-1
    const int tid = threadIdx.x;
    float4 o = {0.f, 0.f, 0.f, 0.f};

    if (flags[row] == 0u) {              // wave-uniform branch (per block)
        *(float4*)&out[(size_t)row * D_ + tid * 4] = o;
        return;
    }

    __shared__ float se[D_];
    __shared__ float sp[D_];
    __shared__ float red[256];
    __shared__ int nspk;
    __shared__ int spk_list[256];

    const int b = row / T_;
    const int t = row % T_;
    const int seg = t / L_;
    const int off = t % L_;
    const int segbase = (b * T_ + seg * L_) * D_;

    for (int i = tid; i < D_; i += 256) {
        float e = start_state[(b * SEG_ + seg) * D_ + i];
        for (int j = 0; j <= off; ++j)
            e = DECAYF * e + OMDF * spikes[segbase + j * D_ + i];
        se[i] = e;
        sp[i] = spikes[(size_t)row * D_ + i];
    }
    if (tid == 0) nspk = 0;
    __syncthreads();

    for (int f0 = 0; f0 < F_; f0 += 256) {
        int f = f0 + tid;
        float mix = 0.f;
        for (int k = 0; k < D_; ++k) mix += se[k] * W1[(size_t)f * D_ + k];
        if (mix > 0.5f) {
            int idx = atomicAdd(&nspk, 1);
            spk_list[idx] = f;
        }
        __syncthreads();
        int n = nspk;
        for (int i = 0; i < n; ++i) {
            int fs = spk_list[i];
            float part = 0.f;
#pragma unroll
            for (int k = 0; k < 4; ++k)
                part += sp[tid * 4 + k] * Wr[(size_t)fs * D_ + tid * 4 + k];
            red[tid] = part;
            __syncthreads();
            for (int sft = 128; sft > 0; sft >>= 1) {
                if (tid < sft) red[tid] += red[tid + sft];
                __syncthreads();
            }
            float r = 1.f / (1.f + expf(-red[0]));
            __syncthreads();
            o.x += r * W2[(size_t)(tid * 4 + 0) * F_ + fs];
            o.y += r * W2[(size_t)(tid * 4 + 1) * F_ + fs];
            o.z += r * W2[(size_t)(tid * 4 + 2) * F_ + fs];
            o.w += r * W2[(size_t)(tid * 4 + 3) * F_ + fs];
        }
        __syncthreads();
        if (tid == 0) nspk = 0;
        __syncthreads();
    }
    *(float4*)&out[(size_t)row * D_ + tid * 4] = o;
}

// ---------------------------------------------------------------------------
extern "C" void kernel_launch(void* const* d_in, const int* in_sizes, int n_in,
                              void* d_out, int out_size, void* d_ws, size_t ws_size,
                              hipStream_t stream) {
    const float* spikes = (const float*)d_in[0];   // [B,T,D]
    const float* W1     = (const float*)d_in[1];   // [F,D]
    const float* W2     = (const float*)d_in[2];   // [D,F]
    const float* Wr     = (const float*)d_in[3];   // [F,D]
    float* out = (float*)d_out;                    // [B,T,D]

    // workspace layout (~14.3 MB total)
    char* ws = (char*)d_ws;
    float* seg_sum      = (float*)ws;                                // 1 MB
    float* start_state  = seg_sum + (size_t)B_ * SEG_ * D_;          // 1 MB
    unsigned int* flags = (unsigned int*)(start_state + (size_t)B_ * SEG_ * D_); // 32 KB
    unsigned char* a_f8 = (unsigned char*)(flags + R_);              // 8 MB, packed
    unsigned char* w_f8 = a_f8 + (size_t)R_ * D_;                    // 4 MB, packed

    kA_prologue<<<KA_W1_BLOCKS + KA_SEG_BLOCKS + KA_FLAG_BLOCKS, 256, 0, stream>>>(
        spikes, W1, w_f8, seg_sum, flags);
    kB_seg_scan<<<(B_ * D_ * 64) / 256, 256, 0, stream>>>(seg_sum, start_state);
    kC_ema_fp8<<<(B_ * SEG_ * D_ / 4) / 256, 256, 0, stream>>>(spikes, start_state, a_f8);

    k2_mfma_flags<<<(R_ / 128) * (F_ / 128), 256, 0, stream>>>(a_f8, w_f8, flags);

    k4_output<<<R_, 256, 0, stream>>>(spikes, start_state, W1, Wr, W2, flags, out);
}

// Round 10
// 174.262 us; speedup vs baseline: 1.1782x; 1.1782x over previous
//
#include <hip/hip_runtime.h>
#include <math.h>

// Problem constants (match reference)
#define B_    4
#define T_    2048
#define D_    1024
#define F_    4096
#define R_    (B_*T_)      // 8192 rows (b,t)
#define SEG_  64           // segments per time-chain
#define L_    (T_/SEG_)    // 32 steps per segment
#define DECAYF 0.9f
#define OMDF   0.1f        // 1 - decay
// Flag threshold below 0.5: the k4 fallback re-tests at exactly 0.5 in fp32,
// so flags only need NO FALSE NEGATIVES. fp8(x8-scaled) GEMM error is
// ~1e-3 RMS (6-sigma ~7e-3); margin 0.05 is ~7x worst plausible error.
#define FLAG_THRESH 0.45f

// ---------------------------------------------------------------------------
// K2 HISTORY (do not re-litigate):
//  R1/R8 depth-4 ROLLED source, 128x128/acc[2][2] (4 streams): compiler
//      collapses to VGPR=104, 4 waves/SIMD -> 44.2 us, FETCH 53 MB.
//      L2-BW-bound: 1 GB redundant L2 traffic / ~23 TB/s == 44 us.
//  R0  2-stage UNROLLED source: VGPR=224, 2 waves/SIMD, 55.7 us.
//  R2  asm-opaque pipeline: CRASHED.  R3 acc[2][4] UNROLLED: SPILLED.
//  R4  __syncthreads lockstep: dedupe proven (FETCH 16 MB) but 69.6 us.
//  R5  raw s_barrier lockstep: 51.6 us. Lockstep ABANDONED.
//  R9  2-phase LDS template: 71.3 us, VGPR 224 — 4 MFMAs/barrier cannot
//      amortize a barrier (catalog template has 64). LDS k2 ABANDONED.
//  R10 (this) acc[2][4] with the ROLLED depth-4 source form (the form that
//      collapses): 6 frag-loads per 8 MFMA tiles = 0.75x L2 traffic,
//      barrier-free. Pre-commit: k2 >= 44 us -> revert to R8, session done.
// ---------------------------------------------------------------------------

typedef __attribute__((ext_vector_type(4)))  int   i32x4;
typedef __attribute__((ext_vector_type(8)))  int   i32x8;
typedef __attribute__((ext_vector_type(16))) float f32x16;

// pack 4 floats into 4 fp8 e4m3 bytes (byte0 = first arg)
__device__ __forceinline__ int pk_fp8x4(float x, float y, float z, float w) {
    int p = 0;
    p = __builtin_amdgcn_cvt_pk_fp8_f32(x, y, p, false);  // bytes 0,1
    p = __builtin_amdgcn_cvt_pk_fp8_f32(z, w, p, true);   // bytes 2,3
    return p;
}

// ---------------------------------------------------------------------------
// PACKED OPERAND LAYOUT: emit fp8 arrays in MFMA-operand tile order:
//   panel P = row>>5 (32 rows), k-chunk C = kbyte>>6 (64 B) -> 2 KB tile at
//   byte ((P*16 + C) * 2048). Within a tile, byte  h*1024 + l*16 + t  holds
//   element [row = P*32 + (l&31)][k = C*64 + (l>>5)*32 + h*16 + t].
// A wave's 32x32x64 fragment load = two 1 KB contiguous global_load_dwordx4
// (lane l at l*16, halves at +0/+1024) — perfectly coalesced, straight to
// VGPRs, zero LDS, zero barriers.
__device__ __forceinline__ size_t pk_off(int row, int d) {
    // byte offset of element [row][d] in the packed layout
    return ((size_t)((row >> 5) * 16 + (d >> 6)) * 2048)
         + ((d >> 4) & 1) * 1024
         + ((row & 31) + ((d >> 5) & 1) * 32) * 16
         + (d & 15);
}

// ---------------------------------------------------------------------------
// KA: fused prologue. Grid-partitioned roles:
//   blocks [0, 4096):       W1 fp32 -> fp8 e4m3 x8, packed operand layout
//   blocks [4096, 4352):    per-segment EMA end-state (seg_sum)
//   blocks [4352, 4384):    zero the 8192 per-row spike flags
#define KA_W1_BLOCKS  4096
#define KA_SEG_BLOCKS 256
#define KA_FLAG_BLOCKS 32

__global__ __launch_bounds__(256)
void kA_prologue(const float* __restrict__ spikes,
                 const float* __restrict__ W1,
                 unsigned char* __restrict__ w_f8,
                 float* __restrict__ seg_sum,
                 unsigned int* __restrict__ flags) {
    const int bid = blockIdx.x;
    const int tid = threadIdx.x;
    if (bid < KA_W1_BLOCKS) {
        int i = bid * 256 + tid;                  // float4 index over W1 [F x D]
        float4 v = ((const float4*)W1)[i];
        int f  = i >> 8;                          // D/4 = 256 groups per row
        int d0 = (i & 255) * 4;
        *(int*)(w_f8 + pk_off(f, d0)) = pk_fp8x4(8.f*v.x, 8.f*v.y, 8.f*v.z, 8.f*v.w);
    } else if (bid < KA_W1_BLOCKS + KA_SEG_BLOCKS) {
        int t = (bid - KA_W1_BLOCKS) * 256 + tid; // B_*SEG_*D_/4 threads
        int dg = t & (D_ / 4 - 1);
        int s = (t >> 8) & (SEG_ - 1);
        int b = t >> 14;
        const float4* sp4 = (const float4*)spikes;
        const int base = (b * T_ + s * L_) * (D_ / 4) + dg;
        float4 e = {0.f, 0.f, 0.f, 0.f};
#pragma unroll 8
        for (int k = 0; k < L_; ++k) {
            float4 x = sp4[base + k * (D_ / 4)];
            e.x = DECAYF * e.x + OMDF * x.x;
            e.y = DECAYF * e.y + OMDF * x.y;
            e.z = DECAYF * e.z + OMDF * x.z;
            e.w = DECAYF * e.w + OMDF * x.w;
        }
        ((float4*)seg_sum)[(b * SEG_ + s) * (D_ / 4) + dg] = e;
    } else {
        int i = (bid - KA_W1_BLOCKS - KA_SEG_BLOCKS) * 256 + tid;
        if (i < R_) flags[i] = 0u;
    }
}

// ---------------------------------------------------------------------------
// KB: weighted Kogge-Stone scan over the 64 segments of each (b,d) chain,
// one chain per 64-lane wave (lane = segment). start_state[s] = scan[s-1].
__global__ __launch_bounds__(256)
void kB_seg_scan(const float* __restrict__ seg_sum,
                 float* __restrict__ start_state) {
    int g = blockIdx.x * 256 + threadIdx.x;   // B_*D_*64 threads
    int s = g & 63;                           // segment = lane
    int c = g >> 6;                           // chain id: 0..B_*D_-1
    int d = c & (D_ - 1);
    int b = c >> 10;
    int idx = (b * SEG_ + s) * D_ + d;
    float v = seg_sum[idx];
    float wp = 0.0343368382f;                 // 0.9^32 (per-segment decay)
#pragma unroll
    for (int off = 1; off < SEG_; off <<= 1) {
        float u = __shfl_up(v, off, 64);
        if (s >= off) v += wp * u;
        wp *= wp;                             // w^1, w^2, w^4, ...
    }
    float pv = __shfl_up(v, 1, 64);
    start_state[idx] = (s == 0) ? 0.f : pv;
}

// ---------------------------------------------------------------------------
// KC: recompute segment-local EMA seeded with start_state; emit fp8 (x8)
// into the packed operand layout.
__global__ __launch_bounds__(256)
void kC_ema_fp8(const float* __restrict__ spikes,
                const float* __restrict__ start_state,
                unsigned char* __restrict__ a_f8) {
    int t = blockIdx.x * 256 + threadIdx.x;            // B_*SEG_*D_/4 threads
    int dg = t & (D_ / 4 - 1);
    int s = (t >> 8) & (SEG_ - 1);
    int b = t >> 14;
    const float4* sp4 = (const float4*)spikes;
    const int base = (b * T_ + s * L_) * (D_ / 4) + dg;
    const int d0 = dg * 4;
    unsigned char* dst = a_f8 + pk_off(b * T_ + s * L_, d0);   // k=0 element
    float4 e = ((const float4*)start_state)[(b * SEG_ + s) * (D_ / 4) + dg];
#pragma unroll 8
    for (int k = 0; k < L_; ++k) {
        float4 x = sp4[base + k * (D_ / 4)];
        e.x = DECAYF * e.x + OMDF * x.x;
        e.y = DECAYF * e.y + OMDF * x.y;
        e.z = DECAYF * e.z + OMDF * x.z;
        e.w = DECAYF * e.w + OMDF * x.w;
        *(int*)(dst + k * 16) = pk_fp8x4(8.f*e.x, 8.f*e.y, 8.f*e.z, 8.f*e.w);
    }
}

// ---------------------------------------------------------------------------
// K2 (R10): MX-fp8 32x32x64 streaming GEMM, NO LDS, NO BARRIERS.
// Block 128x256 (1024 blocks), 4 waves 2m x 2n, wave tile 64x128:
// acc[2][4], 6 operand streams (2 A + 4 B). 6 fragment loads feed 8 MFMAs
// per chunk -> L2 traffic x0.75 vs acc[2][2] (768 MB vs 1 GB) with zero
// timing dependence. Source form is the ROLLED depth-4 pipeline — the form
// R8 proved the compiler collapses to minimal liveness (104 VGPR from a
// nominal 192+). Expected here: ~170-190 VGPR, 2-3 waves/SIMD, no spill.
// Failure signatures: VGPR >= 240 / WRITE_SIZE > 0 (spill) or k2 >= 44 us
// -> revert to R8's k2 permanently.
// NOTE: plain __launch_bounds__(256). Never floor-cap this kernel.
__global__ __launch_bounds__(256)
void k2_mfma_flags(const unsigned char* __restrict__ Ap,  // packed a_f8
                   const unsigned char* __restrict__ Bp,  // packed w_f8
                   unsigned int* __restrict__ flags) {
    const int tid = threadIdx.x;
    const int w = tid >> 6;
    const int lane = tid & 63;
    // XCD-chunked swizzle (T1): 1024 blocks, 8 XCDs, 128 blocks/XCD.
    // Bijective since 1024 % 8 == 0. n-fast: A-panel stays L2-hot across
    // 16 consecutive blocks; B (4 MB) ~L2-resident per XCD.
    const int orig = blockIdx.x;
    const int swz  = (orig & 7) * 128 + (orig >> 3);
    const int m0 = (swz >> 4) * 128;     // 64 m-tiles, slow
    const int n0 = (swz & 15) * 256;     // 16 n-tiles, fast
    const int wm = w >> 1, wn = w & 1;
    const int kg = lane >> 5;

    // Per-lane stream base pointers: 6 streams (2 A tiles, 4 B tiles).
    // Panel P's 16 k-tiles are contiguous (32 KB); k-chunk C reads at +C*2048.
    const unsigned char* a0 = Ap + ((size_t)((m0 >> 5) + wm * 2 + 0) * 16) * 2048 + lane * 16;
    const unsigned char* a1 = Ap + ((size_t)((m0 >> 5) + wm * 2 + 1) * 16) * 2048 + lane * 16;
    const unsigned char* b0 = Bp + ((size_t)((n0 >> 5) + wn * 4 + 0) * 16) * 2048 + lane * 16;
    const unsigned char* b1 = Bp + ((size_t)((n0 >> 5) + wn * 4 + 1) * 16) * 2048 + lane * 16;
    const unsigned char* b2 = Bp + ((size_t)((n0 >> 5) + wn * 4 + 2) * 16) * 2048 + lane * 16;
    const unsigned char* b3 = Bp + ((size_t)((n0 >> 5) + wn * 4 + 3) * 16) * 2048 + lane * 16;

    f32x16 acc[2][4] = {};

#define LDF(p, OFF)                                                         \
    ({ i32x4 lo_ = *(const i32x4*)((p) + (OFF));                            \
       i32x4 hi_ = *(const i32x4*)((p) + (OFF) + 1024);                     \
       (i32x8){lo_.x, lo_.y, lo_.z, lo_.w, hi_.x, hi_.y, hi_.z, hi_.w}; })

#define MFMA1(i, j, AF, BF)                                                 \
    acc[i][j] = __builtin_amdgcn_mfma_scale_f32_32x32x64_f8f6f4(            \
        AF, BF, acc[i][j], 0, 0, 0, 124, 0, 124);

    // 8 MFMAs consuming stage suffix S (A0S,A1S,B0S..B3S).
#define MFMA8(S)                                                            \
    MFMA1(0, 0, A0##S, B0##S) MFMA1(0, 1, A0##S, B1##S)                     \
    MFMA1(0, 2, A0##S, B2##S) MFMA1(0, 3, A0##S, B3##S)                     \
    MFMA1(1, 0, A1##S, B0##S) MFMA1(1, 1, A1##S, B1##S)                     \
    MFMA1(1, 2, A1##S, B2##S) MFMA1(1, 3, A1##S, B3##S)

#define LOADSTAGE(S, OFF)                                                   \
    A0##S = LDF(a0, OFF); A1##S = LDF(a1, OFF);                             \
    B0##S = LDF(b0, OFF); B1##S = LDF(b1, OFF);                             \
    B2##S = LDF(b2, OFF); B3##S = LDF(b3, OFF);

    // Depth-4 software pipeline over 16 k-chunks. Preload C=0..3; each loop
    // iteration consumes 4 stages and reloads them 4 chunks ahead; epilogue
    // consumes C=12..15 with no loads (no OOB, no wrap).
    i32x8 A0s0, A1s0, B0s0, B1s0, B2s0, B3s0;
    i32x8 A0s1, A1s1, B0s1, B1s1, B2s1, B3s1;
    i32x8 A0s2, A1s2, B0s2, B1s2, B2s2, B3s2;
    i32x8 A0s3, A1s3, B0s3, B1s3, B2s3, B3s3;
    LOADSTAGE(s0, 0)
    LOADSTAGE(s1, 2048)
    LOADSTAGE(s2, 4096)
    LOADSTAGE(s3, 6144)

#pragma unroll 1
    for (int p = 0; p < 3; ++p) {
        const size_t off = (size_t)(p + 1) * 8192;   // C = 4p+4 .. 4p+7
        MFMA8(s0)
        LOADSTAGE(s0, off)
        MFMA8(s1)
        LOADSTAGE(s1, off + 2048)
        MFMA8(s2)
        LOADSTAGE(s2, off + 4096)
        MFMA8(s3)
        LOADSTAGE(s3, off + 6144)
    }
    MFMA8(s0)   // C=12
    MFMA8(s1)   // C=13
    MFMA8(s2)   // C=14
    MFMA8(s3)   // C=15
#undef LDF
#undef MFMA1
#undef MFMA8
#undef LOADSTAGE

    // Epilogue: per-row spike flags. 32x32 C/D layout (m74/m101-verified):
    // col = lane&31, row = (reg&3) + 8*(reg>>2) + 4*(lane>>5).
#pragma unroll
    for (int i = 0; i < 2; ++i) {
#pragma unroll
        for (int reg = 0; reg < 16; ++reg) {
            float mx = fmaxf(fmaxf(acc[i][0][reg], acc[i][1][reg]),
                             fmaxf(acc[i][2][reg], acc[i][3][reg]));
            if (mx > FLAG_THRESH) {
                const int rr = (reg & 3) + 8 * (reg >> 2) + 4 * kg;
                atomicOr(&flags[m0 + wm * 64 + i * 32 + rr], 1u);
            }
        }
    }
}

// ---------------------------------------------------------------------------
// K4: one block per (b,t) row. Unflagged rows (the overwhelmingly common
// case) write zeros. Flagged rows take the exact fp32 slow path, rebuilding
// the EMA row from start_state + <=32 spike rows.
__global__ __launch_bounds__(256)
void k4_output(const float* __restrict__ spikes,
               const float* __restrict__ start_state,
               const float* __restrict__ W1,
               const float* __restrict__ Wr,
               const float* __restrict__ W2,
               const unsigned int* __restrict__ flags,
               float* __restrict__ out) {
    const int row = blockIdx.x;          // 0..R_-1
    const int tid = threadIdx.x;
    float4 o = {0.f, 0.f, 0.f, 0.f};

    if (flags[row] == 0u) {              // wave-uniform branch (per block)
        *(float4*)&out[(size_t)row * D_ + tid * 4] = o;
        return;
    }

    __shared__ float se[D_];
    __shared__ float sp[D_];
    __shared__ float red[256];
    __shared__ int nspk;
    __shared__ int spk_list[256];

    const int b = row / T_;
    const int t = row % T_;
    const int seg = t / L_;
    const int off = t % L_;
    const int segbase = (b * T_ + seg * L_) * D_;

    for (int i = tid; i < D_; i += 256) {
        float e = start_state[(b * SEG_ + seg) * D_ + i];
        for (int j = 0; j <= off; ++j)
            e = DECAYF * e + OMDF * spikes[segbase + j * D_ + i];
        se[i] = e;
        sp[i] = spikes[(size_t)row * D_ + i];
    }
    if (tid == 0) nspk = 0;
    __syncthreads();

    for (int f0 = 0; f0 < F_; f0 += 256) {
        int f = f0 + tid;
        float mix = 0.f;
        for (int k = 0; k < D_; ++k) mix += se[k] * W1[(size_t)f * D_ + k];
        if (mix > 0.5f) {
            int idx = atomicAdd(&nspk, 1);
            spk_list[idx] = f;
        }
        __syncthreads();
        int n = nspk;
        for (int i = 0; i < n; ++i) {
            int fs = spk_list[i];
            float part = 0.f;
#pragma unroll
            for (int k = 0; k < 4; ++k)
                part += sp[tid * 4 + k] * Wr[(size_t)fs * D_ + tid * 4 + k];
            red[tid] = part;
            __syncthreads();
            for (int sft = 128; sft > 0; sft >>= 1) {
                if (tid < sft) red[tid] += red[tid + sft];
                __syncthreads();
            }
            float r = 1.f / (1.f + expf(-red[0]));
            __syncthreads();
            o.x += r * W2[(size_t)(tid * 4 + 0) * F_ + fs];
            o.y += r * W2[(size_t)(tid * 4 + 1) * F_ + fs];
            o.z += r * W2[(size_t)(tid * 4 + 2) * F_ + fs];
            o.w += r * W2[(size_t)(tid * 4 + 3) * F_ + fs];
        }
        __syncthreads();
        if (tid == 0) nspk = 0;
        __syncthreads();
    }
    *(float4*)&out[(size_t)row * D_ + tid * 4] = o;
}

// ---------------------------------------------------------------------------
extern "C" void kernel_launch(void* const* d_in, const int* in_sizes, int n_in,
                              void* d_out, int out_size, void* d_ws, size_t ws_size,
                              hipStream_t stream) {
    const float* spikes = (const float*)d_in[0];   // [B,T,D]
    const float* W1     = (const float*)d_in[1];   // [F,D]
    const float* W2     = (const float*)d_in[2];   // [D,F]
    const float* Wr     = (const float*)d_in[3];   // [F,D]
    float* out = (float*)d_out;                    // [B,T,D]

    // workspace layout (~14.3 MB total)
    char* ws = (char*)d_ws;
    float* seg_sum      = (float*)ws;                                // 1 MB
    float* start_state  = seg_sum + (size_t)B_ * SEG_ * D_;          // 1 MB
    unsigned int* flags = (unsigned int*)(start_state + (size_t)B_ * SEG_ * D_); // 32 KB
    unsigned char* a_f8 = (unsigned char*)(flags + R_);              // 8 MB, packed
    unsigned char* w_f8 = a_f8 + (size_t)R_ * D_;                    // 4 MB, packed

    kA_prologue<<<KA_W1_BLOCKS + KA_SEG_BLOCKS + KA_FLAG_BLOCKS, 256, 0, stream>>>(
        spikes, W1, w_f8, seg_sum, flags);
    kB_seg_scan<<<(B_ * D_ * 64) / 256, 256, 0, stream>>>(seg_sum, start_state);
    kC_ema_fp8<<<(B_ * SEG_ * D_ / 4) / 256, 256, 0, stream>>>(spikes, start_state, a_f8);

    // 128x256 block tile -> 1024 blocks
    k2_mfma_flags<<<(R_ / 128) * (F_ / 256), 256, 0, stream>>>(a_f8, w_f8, flags);

    k4_output<<<R_, 256, 0, stream>>>(spikes, start_state, W1, Wr, W2, flags, out);
}

// Round 11
// 165.006 us; speedup vs baseline: 1.2443x; 1.0561x over previous
//
#include <hip/hip_runtime.h>
#include <math.h>

// Problem constants (match reference)
#define B_    4
#define T_    2048
#define D_    1024
#define F_    4096
#define R_    (B_*T_)      // 8192 rows (b,t)
#define SEG_  64           // segments per time-chain
#define L_    (T_/SEG_)    // 32 steps per segment
#define DECAYF 0.9f
#define OMDF   0.1f        // 1 - decay
// Flag threshold below 0.5: the k4 fallback re-tests at exactly 0.5 in fp32,
// so flags only need NO FALSE NEGATIVES. fp8(x8-scaled) GEMM error is
// ~1e-3 RMS (6-sigma ~7e-3); margin 0.05 is ~7x worst plausible error.
#define FLAG_THRESH 0.45f

// ---------------------------------------------------------------------------
// K2 HISTORY (do not re-litigate):
//  R1/R8 depth-4 ROLLED 128x128/acc[2][2]: VGPR 104, 4 w/SIMD, 44.2 us.
//  R10 depth-4 ROLLED 128x256/acc[2][4] (6 streams): VGPR 184, no spill,
//      42.2 us — traffic x0.75 but occupancy 2 w/SIMD cut achieved L2 BW
//      to ~18 TB/s (was ~23). Frontier: traffic vs occupancy.
//  FAILED: R2 asm pipeline (crash), R3 UNROLLED acc[2][4] (spill),
//      R4/R5 lockstep (barrier tax), R9 2-phase LDS (4 MFMAs/barrier
//      can't amortize; catalog template needs 64).
//  R11 (this): only the XCD chunk changes (16m x 8n = exact 4 MB L2 fit;
//      R10's 8m x 16n window was ~4.5 MB). Kernel body untouched.
// ---------------------------------------------------------------------------

typedef __attribute__((ext_vector_type(4)))  int   i32x4;
typedef __attribute__((ext_vector_type(8)))  int   i32x8;
typedef __attribute__((ext_vector_type(16))) float f32x16;

// pack 4 floats into 4 fp8 e4m3 bytes (byte0 = first arg)
__device__ __forceinline__ int pk_fp8x4(float x, float y, float z, float w) {
    int p = 0;
    p = __builtin_amdgcn_cvt_pk_fp8_f32(x, y, p, false);  // bytes 0,1
    p = __builtin_amdgcn_cvt_pk_fp8_f32(z, w, p, true);   // bytes 2,3
    return p;
}

// ---------------------------------------------------------------------------
// PACKED OPERAND LAYOUT: emit fp8 arrays in MFMA-operand tile order:
//   panel P = row>>5 (32 rows), k-chunk C = kbyte>>6 (64 B) -> 2 KB tile at
//   byte ((P*16 + C) * 2048). Within a tile, byte  h*1024 + l*16 + t  holds
//   element [row = P*32 + (l&31)][k = C*64 + (l>>5)*32 + h*16 + t].
// One panel P = a contiguous 32 KB stripe at P*32768. Element [row][d]
// sits at stripe byte:
//   (d>>6)*2048 + ((d>>4)&1)*1024 + ((d>>5)&1)*512 + (row&31)*16 + (d&15)
// R11: producers build the stripe in LDS and store it with coalesced 16-B
// writes (replaces the old scattered 4-B global stores).
__device__ __forceinline__ size_t pk_off(int row, int d) {
    return ((size_t)((row >> 5) * 16 + (d >> 6)) * 2048)
         + ((d >> 4) & 1) * 1024
         + ((row & 31) + ((d >> 5) & 1) * 32) * 16
         + (d & 15);
}

// LDS XOR-swizzle (involution): spreads the stripe's 512-B-strided slots
// across banks. Applied identically on LDS write and LDS read; global
// layout stays linear.
__device__ __forceinline__ int lsw(int o) {
    return o ^ (((o >> 9) & 7) << 4);
}

// ---------------------------------------------------------------------------
// KA: fused prologue. Grid-partitioned roles:
//   blocks [0, 128):     W1 fp32 -> fp8 x8, one 32-row panel per block,
//                        LDS-staged, coalesced 16-B output (R11)
//   blocks [128, 384):   per-segment EMA end-state (seg_sum)
//   blocks [384, 416):   zero the 8192 per-row spike flags
#define KA_W1_BLOCKS  128
#define KA_SEG_BLOCKS 256
#define KA_FLAG_BLOCKS 32

__global__ __launch_bounds__(256)
void kA_prologue(const float* __restrict__ spikes,
                 const float* __restrict__ W1,
                 unsigned char* __restrict__ w_f8,
                 float* __restrict__ seg_sum,
                 unsigned int* __restrict__ flags) {
    const int bid = blockIdx.x;
    const int tid = threadIdx.x;
    __shared__ unsigned char stage[32768];
    if (bid < KA_W1_BLOCKS) {
        // panel P = bid: rows f = P*32 .. P*32+31, all D columns.
        const int d0 = tid * 4;
        const int lbase = (d0 >> 6) * 2048 + ((d0 >> 4) & 1) * 1024
                        + ((d0 >> 5) & 1) * 512 + (d0 & 15);
        const float4* w4 = (const float4*)W1 + (size_t)bid * 32 * 256 + tid;
#pragma unroll 8
        for (int r = 0; r < 32; ++r) {
            float4 v = w4[(size_t)r * 256];          // row P*32+r, coalesced
            *(int*)&stage[lsw(lbase + r * 16)] =
                pk_fp8x4(8.f*v.x, 8.f*v.y, 8.f*v.z, 8.f*v.w);
        }
        __syncthreads();
        i32x4* dst = (i32x4*)(w_f8 + (size_t)bid * 32768);
#pragma unroll
        for (int r = 0; r < 8; ++r) {
            const int byte = (r * 256 + tid) * 16;
            dst[r * 256 + tid] = *(const i32x4*)&stage[lsw(byte)];
        }
    } else if (bid < KA_W1_BLOCKS + KA_SEG_BLOCKS) {
        int t = (bid - KA_W1_BLOCKS) * 256 + tid; // B_*SEG_*D_/4 threads
        int dg = t & (D_ / 4 - 1);
        int s = (t >> 8) & (SEG_ - 1);
        int b = t >> 14;
        const float4* sp4 = (const float4*)spikes;
        const int base = (b * T_ + s * L_) * (D_ / 4) + dg;
        float4 e = {0.f, 0.f, 0.f, 0.f};
#pragma unroll 8
        for (int k = 0; k < L_; ++k) {
            float4 x = sp4[base + k * (D_ / 4)];
            e.x = DECAYF * e.x + OMDF * x.x;
            e.y = DECAYF * e.y + OMDF * x.y;
            e.z = DECAYF * e.z + OMDF * x.z;
            e.w = DECAYF * e.w + OMDF * x.w;
        }
        ((float4*)seg_sum)[(b * SEG_ + s) * (D_ / 4) + dg] = e;
    } else {
        int i = (bid - KA_W1_BLOCKS - KA_SEG_BLOCKS) * 256 + tid;
        if (i < R_) flags[i] = 0u;
    }
}

// ---------------------------------------------------------------------------
// KB: weighted Kogge-Stone scan over the 64 segments of each (b,d) chain,
// one chain per 64-lane wave (lane = segment). start_state[s] = scan[s-1].
__global__ __launch_bounds__(256)
void kB_seg_scan(const float* __restrict__ seg_sum,
                 float* __restrict__ start_state) {
    int g = blockIdx.x * 256 + threadIdx.x;   // B_*D_*64 threads
    int s = g & 63;                           // segment = lane
    int c = g >> 6;                           // chain id: 0..B_*D_-1
    int d = c & (D_ - 1);
    int b = c >> 10;
    int idx = (b * SEG_ + s) * D_ + d;
    float v = seg_sum[idx];
    float wp = 0.0343368382f;                 // 0.9^32 (per-segment decay)
#pragma unroll
    for (int off = 1; off < SEG_; off <<= 1) {
        float u = __shfl_up(v, off, 64);
        if (s >= off) v += wp * u;
        wp *= wp;                             // w^1, w^2, w^4, ...
    }
    float pv = __shfl_up(v, 1, 64);
    start_state[idx] = (s == 0) ? 0.f : pv;
}

// ---------------------------------------------------------------------------
// KC (R11): one block per (b,s) chain (256 blocks — same grid as before;
// the old code's block bid also covered exactly (b=bid>>6, s=bid&63)).
// Rows b*T+s*32..+31 form exactly panel P = b*64+s, a contiguous 32 KB
// stripe. Compute the EMA + fp8 pack into LDS (XOR-swizzled), then store
// the stripe with coalesced 16-B writes.
__global__ __launch_bounds__(256)
void kC_ema_fp8(const float* __restrict__ spikes,
                const float* __restrict__ start_state,
                unsigned char* __restrict__ a_f8) {
    const int bs = blockIdx.x;               // b*SEG + s  (== panel P)
    const int b = bs >> 6, s = bs & 63;
    const int tid = threadIdx.x;
    const int d0 = tid * 4;
    __shared__ unsigned char stage[32768];
    const int lbase = (d0 >> 6) * 2048 + ((d0 >> 4) & 1) * 1024
                    + ((d0 >> 5) & 1) * 512 + (d0 & 15);
    const float4* sp4 = (const float4*)spikes;
    const int base = (b * T_ + s * L_) * (D_ / 4) + tid;
    float4 e = ((const float4*)start_state)[bs * (D_ / 4) + tid];
#pragma unroll 8
    for (int k = 0; k < L_; ++k) {
        float4 x = sp4[base + k * (D_ / 4)];
        e.x = DECAYF * e.x + OMDF * x.x;
        e.y = DECAYF * e.y + OMDF * x.y;
        e.z = DECAYF * e.z + OMDF * x.z;
        e.w = DECAYF * e.w + OMDF * x.w;
        *(int*)&stage[lsw(lbase + k * 16)] =
            pk_fp8x4(8.f*e.x, 8.f*e.y, 8.f*e.z, 8.f*e.w);
    }
    __syncthreads();
    i32x4* dst = (i32x4*)(a_f8 + (size_t)bs * 32768);
#pragma unroll
    for (int r = 0; r < 8; ++r) {
        const int byte = (r * 256 + tid) * 16;
        dst[r * 256 + tid] = *(const i32x4*)&stage[lsw(byte)];
    }
}

// ---------------------------------------------------------------------------
// K2 (R11 = R10 body, new swizzle): MX-fp8 32x32x64 streaming GEMM, NO LDS,
// NO BARRIERS. Block 128x256 (1024 blocks), 4 waves 2m x 2n, wave tile
// 64x128: acc[2][4], 6 operand streams. ROLLED depth-4 pipeline (the form
// the compiler collapses to minimal liveness — VGPR 184, no spill, R10).
// XCD chunk now 16m x 8n: A 2 MB + B 2 MB = exact L2 fit (R10's 8m x 16n
// resident window was ~4.5 MB > 4 MB).
// NOTE: plain __launch_bounds__(256). Never floor-cap this kernel.
__global__ __launch_bounds__(256)
void k2_mfma_flags(const unsigned char* __restrict__ Ap,  // packed a_f8
                   const unsigned char* __restrict__ Bp,  // packed w_f8
                   unsigned int* __restrict__ flags) {
    const int tid = threadIdx.x;
    const int w = tid >> 6;
    const int lane = tid & 63;
    // XCD-chunked swizzle: 1024 blocks, 8 XCDs, 128 blocks/XCD as 16m x 8n.
    // Bijective: mt = (xcd>>1)*16 + id>>3, nt = (xcd&1)*8 + (id&7).
    const int orig = blockIdx.x;
    const int xcd  = orig & 7;
    const int id   = orig >> 3;                     // 0..127 within XCD
    const int mt   = (xcd >> 1) * 16 + (id >> 3);   // 0..63 (m-tile)
    const int nt   = (xcd & 1) * 8 + (id & 7);      // 0..15 (n-tile, fast)
    const int m0 = mt * 128;
    const int n0 = nt * 256;
    const int wm = w >> 1, wn = w & 1;
    const int kg = lane >> 5;

    // Per-lane stream base pointers: 6 streams (2 A tiles, 4 B tiles).
    // Panel P's 16 k-tiles are contiguous (32 KB); k-chunk C reads at +C*2048.
    const unsigned char* a0 = Ap + ((size_t)((m0 >> 5) + wm * 2 + 0) * 16) * 2048 + lane * 16;
    const unsigned char* a1 = Ap + ((size_t)((m0 >> 5) + wm * 2 + 1) * 16) * 2048 + lane * 16;
    const unsigned char* b0 = Bp + ((size_t)((n0 >> 5) + wn * 4 + 0) * 16) * 2048 + lane * 16;
    const unsigned char* b1 = Bp + ((size_t)((n0 >> 5) + wn * 4 + 1) * 16) * 2048 + lane * 16;
    const unsigned char* b2 = Bp + ((size_t)((n0 >> 5) + wn * 4 + 2) * 16) * 2048 + lane * 16;
    const unsigned char* b3 = Bp + ((size_t)((n0 >> 5) + wn * 4 + 3) * 16) * 2048 + lane * 16;

    f32x16 acc[2][4] = {};

#define LDF(p, OFF)                                                         \
    ({ i32x4 lo_ = *(const i32x4*)((p) + (OFF));                            \
       i32x4 hi_ = *(const i32x4*)((p) + (OFF) + 1024);                     \
       (i32x8){lo_.x, lo_.y, lo_.z, lo_.w, hi_.x, hi_.y, hi_.z, hi_.w}; })

#define MFMA1(i, j, AF, BF)                                                 \
    acc[i][j] = __builtin_amdgcn_mfma_scale_f32_32x32x64_f8f6f4(            \
        AF, BF, acc[i][j], 0, 0, 0, 124, 0, 124);

#define MFMA8(S)                                                            \
    MFMA1(0, 0, A0##S, B0##S) MFMA1(0, 1, A0##S, B1##S)                     \
    MFMA1(0, 2, A0##S, B2##S) MFMA1(0, 3, A0##S, B3##S)                     \
    MFMA1(1, 0, A1##S, B0##S) MFMA1(1, 1, A1##S, B1##S)                     \
    MFMA1(1, 2, A1##S, B2##S) MFMA1(1, 3, A1##S, B3##S)

#define LOADSTAGE(S, OFF)                                                   \
    A0##S = LDF(a0, OFF); A1##S = LDF(a1, OFF);                             \
    B0##S = LDF(b0, OFF); B1##S = LDF(b1, OFF);                             \
    B2##S = LDF(b2, OFF); B3##S = LDF(b3, OFF);

    // Depth-4 software pipeline over 16 k-chunks. Preload C=0..3; each loop
    // iteration consumes 4 stages and reloads them 4 chunks ahead; epilogue
    // consumes C=12..15 with no loads (no OOB, no wrap).
    i32x8 A0s0, A1s0, B0s0, B1s0, B2s0, B3s0;
    i32x8 A0s1, A1s1, B0s1, B1s1, B2s1, B3s1;
    i32x8 A0s2, A1s2, B0s2, B1s2, B2s2, B3s2;
    i32x8 A0s3, A1s3, B0s3, B1s3, B2s3, B3s3;
    LOADSTAGE(s0, 0)
    LOADSTAGE(s1, 2048)
    LOADSTAGE(s2, 4096)
    LOADSTAGE(s3, 6144)

#pragma unroll 1
    for (int p = 0; p < 3; ++p) {
        const size_t off = (size_t)(p + 1) * 8192;   // C = 4p+4 .. 4p+7
        MFMA8(s0)
        LOADSTAGE(s0, off)
        MFMA8(s1)
        LOADSTAGE(s1, off + 2048)
        MFMA8(s2)
        LOADSTAGE(s2, off + 4096)
        MFMA8(s3)
        LOADSTAGE(s3, off + 6144)
    }
    MFMA8(s0)   // C=12
    MFMA8(s1)   // C=13
    MFMA8(s2)   // C=14
    MFMA8(s3)   // C=15
#undef LDF
#undef MFMA1
#undef MFMA8
#undef LOADSTAGE

    // Epilogue: per-row spike flags. 32x32 C/D layout (m74/m101-verified):
    // col = lane&31, row = (reg&3) + 8*(reg>>2) + 4*(lane>>5).
#pragma unroll
    for (int i = 0; i < 2; ++i) {
#pragma unroll
        for (int reg = 0; reg < 16; ++reg) {
            float mx = fmaxf(fmaxf(acc[i][0][reg], acc[i][1][reg]),
                             fmaxf(acc[i][2][reg], acc[i][3][reg]));
            if (mx > FLAG_THRESH) {
                const int rr = (reg & 3) + 8 * (reg >> 2) + 4 * kg;
                atomicOr(&flags[m0 + wm * 64 + i * 32 + rr], 1u);
            }
        }
    }
}

// ---------------------------------------------------------------------------
// K4: one block per (b,t) row. Unflagged rows (the overwhelmingly common
// case) write zeros. Flagged rows take the exact fp32 slow path, rebuilding
// the EMA row from start_state + <=32 spike rows.
__global__ __launch_bounds__(256)
void k4_output(const float* __restrict__ spikes,
               const float* __restrict__ start_state,
               const float* __restrict__ W1,
               const float* __restrict__ Wr,
               const float* __restrict__ W2,
               const unsigned int* __restrict__ flags,
               float* __restrict__ out) {
    const int row = blockIdx.x;          // 0..R_-1
    const int tid = threadIdx.x;
    float4 o = {0.f, 0.f, 0.f, 0.f};

    if (flags[row] == 0u) {              // wave-uniform branch (per block)
        *(float4*)&out[(size_t)row * D_ + tid * 4] = o;
        return;
    }

    __shared__ float se[D_];
    __shared__ float sp[D_];
    __shared__ float red[256];
    __shared__ int nspk;
    __shared__ int spk_list[256];

    const int b = row / T_;
    const int t = row % T_;
    const int seg = t / L_;
    const int off = t % L_;
    const int segbase = (b * T_ + seg * L_) * D_;

    for (int i = tid; i < D_; i += 256) {
        float e = start_state[(b * SEG_ + seg) * D_ + i];
        for (int j = 0; j <= off; ++j)
            e = DECAYF * e + OMDF * spikes[segbase + j * D_ + i];
        se[i] = e;
        sp[i] = spikes[(size_t)row * D_ + i];
    }
    if (tid == 0) nspk = 0;
    __syncthreads();

    for (int f0 = 0; f0 < F_; f0 += 256) {
        int f = f0 + tid;
        float mix = 0.f;
        for (int k = 0; k < D_; ++k) mix += se[k] * W1[(size_t)f * D_ + k];
        if (mix > 0.5f) {
            int idx = atomicAdd(&nspk, 1);
            spk_list[idx] = f;
        }
        __syncthreads();
        int n = nspk;
        for (int i = 0; i < n; ++i) {
            int fs = spk_list[i];
            float part = 0.f;
#pragma unroll
            for (int k = 0; k < 4; ++k)
                part += sp[tid * 4 + k] * Wr[(size_t)fs * D_ + tid * 4 + k];
            red[tid] = part;
            __syncthreads();
            for (int sft = 128; sft > 0; sft >>= 1) {
                if (tid < sft) red[tid] += red[tid + sft];
                __syncthreads();
            }
            float r = 1.f / (1.f + expf(-red[0]));
            __syncthreads();
            o.x += r * W2[(size_t)(tid * 4 + 0) * F_ + fs];
            o.y += r * W2[(size_t)(tid * 4 + 1) * F_ + fs];
            o.z += r * W2[(size_t)(tid * 4 + 2) * F_ + fs];
            o.w += r * W2[(size_t)(tid * 4 + 3) * F_ + fs];
        }
        __syncthreads();
        if (tid == 0) nspk = 0;
        __syncthreads();
    }
    *(float4*)&out[(size_t)row * D_ + tid * 4] = o;
}

// ---------------------------------------------------------------------------
extern "C" void kernel_launch(void* const* d_in, const int* in_sizes, int n_in,
                              void* d_out, int out_size, void* d_ws, size_t ws_size,
                              hipStream_t stream) {
    const float* spikes = (const float*)d_in[0];   // [B,T,D]
    const float* W1     = (const float*)d_in[1];   // [F,D]
    const float* W2     = (const float*)d_in[2];   // [D,F]
    const float* Wr     = (const float*)d_in[3];   // [F,D]
    float* out = (float*)d_out;                    // [B,T,D]

    // workspace layout (~14.3 MB total)
    char* ws = (char*)d_ws;
    float* seg_sum      = (float*)ws;                                // 1 MB
    float* start_state  = seg_sum + (size_t)B_ * SEG_ * D_;          // 1 MB
    unsigned int* flags = (unsigned int*)(start_state + (size_t)B_ * SEG_ * D_); // 32 KB
    unsigned char* a_f8 = (unsigned char*)(flags + R_);              // 8 MB, packed
    unsigned char* w_f8 = a_f8 + (size_t)R_ * D_;                    // 4 MB, packed

    kA_prologue<<<KA_W1_BLOCKS + KA_SEG_BLOCKS + KA_FLAG_BLOCKS, 256, 0, stream>>>(
        spikes, W1, w_f8, seg_sum, flags);
    kB_seg_scan<<<(B_ * D_ * 64) / 256, 256, 0, stream>>>(seg_sum, start_state);
    kC_ema_fp8<<<B_ * SEG_, 256, 0, stream>>>(spikes, start_state, a_f8);

    // 128x256 block tile -> 1024 blocks
    k2_mfma_flags<<<(R_ / 128) * (F_ / 256), 256, 0, stream>>>(a_f8, w_f8, flags);

    k4_output<<<R_, 256, 0, stream>>>(spikes, start_state, W1, Wr, W2, flags, out);
}